// Round 6
// baseline (3611.420 us; speedup 1.0000x reference)
//
#include <hip/hip_runtime.h>
#include <stdint.h>

// ---------------- problem constants ----------------
#define B_   256
#define T_   512
#define CIN  64
#define H_   256
#define G4   1024   // 4*H
#define NC   6

// ---------------- WG geometry ----------------------
#define MB   32               // batch rows per WG
#define NHU  16               // hidden units per WG
#define NBG  (B_/MB)          // 8 batch groups
#define NHG  (H_/NHU)         // 16 hidden groups
#define NWG  (NBG*NHG)        // 128 workgroups
#define SLOTS 4               // pub ring depth (layer0 may lead layer1 by 3)

typedef __bf16 bf16x8 __attribute__((ext_vector_type(8)));
typedef __bf16 bf16x4 __attribute__((ext_vector_type(4)));
typedef float  f32x4  __attribute__((ext_vector_type(4)));
typedef unsigned u32x4 __attribute__((ext_vector_type(4)));   // asm-bindable 16B payload

// ---------------- workspace layout (bytes) ---------
#define OFF_XBF   ((size_t)0)
#define SZ_XBF    ((size_t)B_*T_*CIN*2)          // 16 MB
#define OFF_W0X   (OFF_XBF + SZ_XBF)
#define SZ_W0X    ((size_t)G4*CIN*2)             // 128 KB
#define OFF_W0H   (OFF_W0X + SZ_W0X)
#define SZ_WH     ((size_t)G4*H_*2)              // 512 KB
#define OFF_W1X   (OFF_W0H + SZ_WH)
#define OFF_W1H   (OFF_W1X + SZ_WH)
#define OFF_B0    (OFF_W1H + SZ_WH)
#define OFF_B1    (OFF_B0 + 4096)
#define OFF_APUB  (OFF_B1 + 4096)
#define SZ_PUB    ((size_t)SLOTS*B_*H_*2)        // 512 KB per array (4 slots)
#define OFF_BPUB  (OFF_APUB + SZ_PUB)
#define OFF_SYNC  (OFF_BPUB + SZ_PUB)
#define SYNC_WORDS 4096                          // 16 KB zeroed every launch

#define DYN_LDS_ELEMS (4096 + 3*16384)           // 53248 bf16
#define DYN_LDS_BYTES (DYN_LDS_ELEMS*2)          // 106496 B

__device__ __forceinline__ f32x4 MFMA(bf16x8 a, bf16x8 b, f32x4 c) {
  return __builtin_amdgcn_mfma_f32_16x16x32_bf16(a, b, c, 0, 0, 0);
}
__device__ __forceinline__ float fsig(float x) { return 1.f/(1.f + __expf(-x)); }
__device__ __forceinline__ float ftanh_(float x) {
  float xx = fminf(fmaxf(x, -15.f), 15.f);
  float t = __expf(2.f*xx);
  return (t-1.f)/(t+1.f);
}

// batched 8x16B coherence-point loads (MALL), no wait inside
__device__ __forceinline__ void load8_c(const __bf16* b, bf16x8 (&r)[8]) {
  const __bf16 *p0=b,      *p1=b+32,  *p2=b+64,  *p3=b+96,
               *p4=b+128,  *p5=b+160, *p6=b+192, *p7=b+224;
  asm volatile(
    "global_load_dwordx4 %0, %8, off sc0 sc1\n\t"
    "global_load_dwordx4 %1, %9, off sc0 sc1\n\t"
    "global_load_dwordx4 %2, %10, off sc0 sc1\n\t"
    "global_load_dwordx4 %3, %11, off sc0 sc1\n\t"
    "global_load_dwordx4 %4, %12, off sc0 sc1\n\t"
    "global_load_dwordx4 %5, %13, off sc0 sc1\n\t"
    "global_load_dwordx4 %6, %14, off sc0 sc1\n\t"
    "global_load_dwordx4 %7, %15, off sc0 sc1"
    : "=&v"(r[0]), "=&v"(r[1]), "=&v"(r[2]), "=&v"(r[3]),
      "=&v"(r[4]), "=&v"(r[5]), "=&v"(r[6]), "=&v"(r[7])
    : "v"(p0), "v"(p1), "v"(p2), "v"(p3), "v"(p4), "v"(p5), "v"(p6), "v"(p7)
    : "memory");
}
__device__ __forceinline__ void waitv0() { asm volatile("s_waitcnt vmcnt(0)" ::: "memory"); }
__device__ __forceinline__ void sbar0()  { __builtin_amdgcn_sched_barrier(0); }

// wave-parallel flag poll: fb[0..31]=layer0 stamps, fb[32..63]=layer1 stamps.
// Wait until all L0 stamps >= tA and all L1 stamps >= tB. Plain coherent loads,
// no RMW anywhere.
__device__ __forceinline__ void poll_flags(const unsigned* fb, unsigned tA, unsigned tB) {
  const int lane = threadIdx.x & 63;
  const unsigned thr = (lane < 32) ? tA : tB;
  const unsigned* p = fb + lane;
  for (;;) {
    unsigned v;
    asm volatile("global_load_dword %0, %1, off sc0 sc1\n\ts_waitcnt vmcnt(0)"
                 : "=&v"(v) : "v"(p) : "memory");
    if (__ballot(v >= thr) == ~0ull) return;
    __builtin_amdgcn_s_sleep(1);
  }
}
// per-wave arrival stamp: plain coherent store (no atomic)
__device__ __forceinline__ void store_flag(unsigned* p, unsigned v) {
  asm volatile("global_store_dword %0, %1, off sc0 sc1" :: "v"(p), "v"(v) : "memory");
}
// packed 16B publish store to the coherence point
__device__ __forceinline__ void st16_pub(__bf16* p, u32x4 v) {
  asm volatile("global_store_dwordx4 %0, %1, off sc0 sc1" :: "v"(p), "v"(v) : "memory");
}

// ---------------- prep: x -> bf16 ------------------
__global__ void k_prep_x(const float* __restrict__ x, __bf16* __restrict__ xbf) {
  int i = blockIdx.x * blockDim.x + threadIdx.x;
  const int n4 = (B_*T_*CIN)/4;
  if (i >= n4) return;
  float4 v = reinterpret_cast<const float4*>(x)[i];
  bf16x4 o;
  o[0] = (__bf16)v.x; o[1] = (__bf16)v.y; o[2] = (__bf16)v.z; o[3] = (__bf16)v.w;
  reinterpret_cast<bf16x4*>(xbf)[i] = o;
}

// ---------------- prep: weights into MFMA-fragment order ----------------
// target layout per matrix: [hj][ct][ks][sub][col][j]  (j=8 contiguous bf16)
// element = W[g=ct*256+hj*16+col][k=ks*32+sub*8+j]
__global__ void k_prep_w(const float* __restrict__ Wih0, const float* __restrict__ Whh0,
                         const float* __restrict__ Wih1, const float* __restrict__ Whh1,
                         __bf16* __restrict__ w0x, __bf16* __restrict__ w0h,
                         __bf16* __restrict__ w1x, __bf16* __restrict__ w1h) {
  int e = blockIdx.x * blockDim.x + threadIdx.x;
  const int E0 = G4*CIN, E1 = G4*H_;
  const float* W; __bf16* dst; int K; int idx;
  if      (e < E0)        { W = Wih0; dst = w0x; K = CIN; idx = e; }
  else if (e < E0+E1)     { W = Whh0; dst = w0h; K = H_;  idx = e - E0; }
  else if (e < E0+2*E1)   { W = Wih1; dst = w1x; K = H_;  idx = e - E0 - E1; }
  else if (e < E0+3*E1)   { W = Whh1; dst = w1h; K = H_;  idx = e - E0 - 2*E1; }
  else return;
  const int kb = K >> 5;                  // K/32
  int j   = idx & 7;
  int cl  = (idx >> 3) & 15;
  int sb  = (idx >> 7) & 3;
  int ks  = (idx >> 9) % kb;
  int ct  = (idx / (512*kb)) & 3;
  int hj  =  idx / (2048*kb);
  int g  = ct*256 + hj*16 + cl;
  int kk = ks*32 + sb*8 + j;
  dst[idx] = (__bf16)W[(size_t)g*K + kk];
}

// ---------------- prep: biases, zero pub + sync areas ----------------
__global__ void k_prep_misc(const float* __restrict__ bih0, const float* __restrict__ bhh0,
                            const float* __restrict__ bih1, const float* __restrict__ bhh1,
                            float* __restrict__ bias0, float* __restrict__ bias1,
                            unsigned* __restrict__ zpub, unsigned* __restrict__ syncw) {
  int i = blockIdx.x * blockDim.x + threadIdx.x;
  if (i < G4) bias0[i] = bih0[i] + bhh0[i];
  else if (i < 2*G4) { int j = i - G4; bias1[j] = bih1[j] + bhh1[j]; }
  const int PW = (int)((2*SZ_PUB)/4);
  int zi = i - 2*G4;
  if (zi >= 0 && zi < PW) zpub[zi] = 0u;
  int zf = i - 2*G4 - PW;
  if (zf >= 0 && zf < SYNC_WORDS) syncw[zf] = 0u;
}

// ---------------- persistent pipelined LSTM ----------------
// sync word map: flags for bg at sync[bg*64 .. bg*64+63]
//   [0..31]  layer0 wave stamps (index hj*2+mt), [32..63] layer1 wave stamps
__global__ void __launch_bounds__(256, 1) k_lstm(
    const __bf16* __restrict__ xbf,
    const __bf16* __restrict__ w0x_g, const __bf16* __restrict__ w0h_g,
    const __bf16* __restrict__ w1x_g, const __bf16* __restrict__ w1h_g,
    const float* __restrict__ bias0, const float* __restrict__ bias1,
    __bf16* __restrict__ apub, __bf16* __restrict__ bpub,
    unsigned* __restrict__ sync,
    const float* __restrict__ Wfc, const float* __restrict__ bfc,
    float* __restrict__ out)
{
  extern __shared__ __bf16 lds[];
  __bf16* l0x = lds;                 // 4096  elems
  __bf16* l0h = lds + 4096;          // 16384
  __bf16* l1x = lds + 20480;         // 16384
  __bf16* l1h = lds + 36864;         // 16384
  __shared__ float  s_log[MB][NC];
  __shared__ __bf16 s_stage[4][16][24];   // per-wave publish transpose (padded)

  const int tid   = threadIdx.x;
  const int bid   = blockIdx.x;
  const int bg    = bid & 7;         // L2-locality heuristic only (correctness-neutral)
  const int hj    = bid >> 3;        // 0..15 hidden group (16 units)
  const int wave  = tid >> 6;
  const int lane  = tid & 63;
  const int layer = wave >> 1;       // waves 0,1 -> layer0 ; waves 2,3 -> layer1
  const int mt    = wave & 1;        // m-tile within the 32-row batch group
  const int col   = lane & 15;       // MFMA A-row / D-col index
  const int sub   = lane >> 4;       // MFMA k-group
  const int brow  = bg*MB + mt*16;

  unsigned* fb    = sync + (size_t)bg*64;               // this bg's flag block
  unsigned* myfl  = fb + layer*32 + hj*2 + mt;          // this wave's stamp word

  // stage weights LDS-resident for the whole run
  {
    const uint4* s; uint4* d;
    s = (const uint4*)(w0x_g + (size_t)hj*4096);  d = (uint4*)l0x;
    for (int i = tid; i < 512;  i += 256) d[i] = s[i];
    s = (const uint4*)(w0h_g + (size_t)hj*16384); d = (uint4*)l0h;
    for (int i = tid; i < 2048; i += 256) d[i] = s[i];
    s = (const uint4*)(w1x_g + (size_t)hj*16384); d = (uint4*)l1x;
    for (int i = tid; i < 2048; i += 256) d[i] = s[i];
    s = (const uint4*)(w1h_g + (size_t)hj*16384); d = (uint4*)l1h;
    for (int i = tid; i < 2048; i += 256) d[i] = s[i];
  }
  __syncthreads();

  // per-lane gate biases (unit = hj*16+col), per this wave's layer
  float bs0, bs1, bs2, bs3;
  {
    const float* bp = layer ? bias1 : bias0;
    bs0 = bp[0*256 + hj*16 + col];
    bs1 = bp[1*256 + hj*16 + col];
    bs2 = bp[2*256 + hj*16 + col];
    bs3 = bp[3*256 + hj*16 + col];
  }
  float cst[4] = {0.f, 0.f, 0.f, 0.f};

  // barrier-free per-wave time loop (no atomics, no block barriers)
  for (int k = 0; k <= T_; ++k) {
    const bool act0 = (layer == 0) && (k < T_);
    const bool act1 = (layer == 1) && (k >= 1);
    f32x4 acc0 = {0,0,0,0}, acc1 = {0,0,0,0}, acc2 = {0,0,0,0}, acc3 = {0,0,0,0};

    // phase A (independent of published data): x-input GEMM, K=64
    if (act0) {
      const __bf16* xr = xbf + ((size_t)(brow+col)*T_ + k)*CIN + sub*8;
      const __bf16* wb = l0x + sub*128 + col*8;
#pragma unroll
      for (int ks = 0; ks < 2; ++ks) {
        bf16x8 a = *(const bf16x8*)(xr + ks*32);
        acc0 = MFMA(a, *(const bf16x8*)(wb + ks*512 +    0), acc0);
        acc1 = MFMA(a, *(const bf16x8*)(wb + ks*512 + 1024), acc1);
        acc2 = MFMA(a, *(const bf16x8*)(wb + ks*512 + 2048), acc2);
        acc3 = MFMA(a, *(const bf16x8*)(wb + ks*512 + 3072), acc3);
      }
    }

    // rendezvous (per wave): all L0 stamps >= tA  &&  all L1 stamps >= tB
    if (act0) {
      if (k > 0) {
        unsigned tA = (unsigned)k;                         // layer0 done iter k-1
        unsigned tB = (k >= 2) ? (unsigned)(k-2) : 0u;     // ring write-after-read guard
        poll_flags(fb, tA, tB);
      }
    } else if (act1) {
      poll_flags(fb, (unsigned)k, (unsigned)k);            // both layers done iter k-1
    }

    // phase B: recurrent GEMMs
    if (act0) {            // gates0 += a_{k-1} @ Whh0^T
      const __bf16* a_prev = apub + (size_t)((k-1)&3)*(B_*H_);
      bf16x8 ra[8];
      load8_c(a_prev + (size_t)(brow+col)*H_ + sub*8, ra);
      waitv0(); sbar0();
      const __bf16* wb = l0h + sub*128 + col*8;
#pragma unroll
      for (int ks = 0; ks < 8; ++ks) {
        acc0 = MFMA(ra[ks], *(const bf16x8*)(wb + ks*512 +     0), acc0);
        acc1 = MFMA(ra[ks], *(const bf16x8*)(wb + ks*512 +  4096), acc1);
        acc2 = MFMA(ra[ks], *(const bf16x8*)(wb + ks*512 +  8192), acc2);
        acc3 = MFMA(ra[ks], *(const bf16x8*)(wb + ks*512 + 12288), acc3);
      }
    } else if (act1) {     // gates1 = a_{k-1} @ Wih1^T + b_{k-2} @ Whh1^T
      const __bf16* a_prev = apub + (size_t)((k-1)&3)*(B_*H_);
      const __bf16* b_prev = bpub + (size_t)((k-2)&3)*(B_*H_);
      bf16x8 ra[8], rb[8];
      load8_c(a_prev + (size_t)(brow+col)*H_ + sub*8, ra);
      load8_c(b_prev + (size_t)(brow+col)*H_ + sub*8, rb);
      waitv0(); sbar0();
      const __bf16* w1 = l1x + sub*128 + col*8;
      const __bf16* w2 = l1h + sub*128 + col*8;
#pragma unroll
      for (int ks = 0; ks < 8; ++ks) {
        acc0 = MFMA(ra[ks], *(const bf16x8*)(w1 + ks*512 +     0), acc0);
        acc1 = MFMA(ra[ks], *(const bf16x8*)(w1 + ks*512 +  4096), acc1);
        acc2 = MFMA(ra[ks], *(const bf16x8*)(w1 + ks*512 +  8192), acc2);
        acc3 = MFMA(ra[ks], *(const bf16x8*)(w1 + ks*512 + 12288), acc3);
      }
#pragma unroll
      for (int ks = 0; ks < 8; ++ks) {
        acc0 = MFMA(rb[ks], *(const bf16x8*)(w2 + ks*512 +     0), acc0);
        acc1 = MFMA(rb[ks], *(const bf16x8*)(w2 + ks*512 +  4096), acc1);
        acc2 = MFMA(rb[ks], *(const bf16x8*)(w2 + ks*512 +  8192), acc2);
        acc3 = MFMA(rb[ks], *(const bf16x8*)(w2 + ks*512 + 12288), acc3);
      }
    }

    // LSTM cell + packed publish (wave-local LDS transpose -> one 16B store/lane)
    if (act0 || act1) {
      const int slot = act0 ? (k & 3) : ((k - 1) & 3);
      __bf16* dst = (act0 ? apub : bpub) + (size_t)slot*(B_*H_);
#pragma unroll
      for (int q = 0; q < 4; ++q) {
        float gi = acc0[q] + bs0;
        float gf = acc1[q] + bs1;
        float gg = acc2[q] + bs2;
        float go = acc3[q] + bs3;
        float si = fsig(gi), sf = fsig(gf), sg = ftanh_(gg), so = fsig(go);
        float c = sf*cst[q] + si*sg;
        cst[q] = c;
        s_stage[wave][sub*4+q][col] = (__bf16)(so * ftanh_(c));
      }
      asm volatile("s_waitcnt lgkmcnt(0)" ::: "memory");
      sbar0();
      if (lane < 32) {
        const int r16 = lane >> 1, half = lane & 1;
        u32x4 packed = *reinterpret_cast<const u32x4*>(&s_stage[wave][r16][half*8]);
        __bf16* pa = dst + (size_t)(bg*MB + mt*16 + r16)*H_ + hj*16 + half*8;
        st16_pub(pa, packed);
      }
    }

    // arrive: drain own stores, then plain per-wave stamp store (no atomic)
    waitv0();
    if (lane == 0) store_flag(myfl, (unsigned)(k + 1));
  }

  // ---------------- final FC + softmax (one WG per batch group) ----------------
  if (hj == 0) {
    poll_flags(fb, 0u, (unsigned)(T_ + 1));   // all layer1 waves fully done
    if (tid < MB*NC) {
      int r = tid / NC, cl = tid % NC;
      const __bf16* hr = bpub + (size_t)((T_-1)&3)*(B_*H_) + (size_t)(bg*MB + r)*H_;
      const float*  wr = Wfc + (size_t)cl*H_;
      float s = bfc[cl];
      for (int c8 = 0; c8 < 32; ++c8) {
        bf16x8 v;
        const __bf16* p = hr + c8*8;
        asm volatile("global_load_dwordx4 %0, %1, off sc0 sc1\n\ts_waitcnt vmcnt(0)"
                     : "=&v"(v) : "v"(p) : "memory");
#pragma unroll
        for (int j = 0; j < 8; ++j) s = fmaf((float)v[j], wr[c8*8+j], s);
      }
      s_log[r][cl] = s;
    }
    __syncthreads();
    if (tid < MB) {
      float mx = s_log[tid][0];
#pragma unroll
      for (int c2 = 1; c2 < NC; ++c2) mx = fmaxf(mx, s_log[tid][c2]);
      float e[NC]; float se = 0.f;
#pragma unroll
      for (int c2 = 0; c2 < NC; ++c2) { e[c2] = __expf(s_log[tid][c2] - mx); se += e[c2]; }
      float inv = 1.f/se;
#pragma unroll
      for (int c2 = 0; c2 < NC; ++c2) out[(size_t)(bg*MB + tid)*NC + c2] = e[c2]*inv;
    }
  }
}

// ---------------- host launcher ----------------
extern "C" void kernel_launch(void* const* d_in, const int* in_sizes, int n_in,
                              void* d_out, int out_size, void* d_ws, size_t ws_size,
                              hipStream_t stream) {
  const float* x    = (const float*)d_in[0];
  const float* Wih0 = (const float*)d_in[1];
  const float* Whh0 = (const float*)d_in[2];
  const float* bih0 = (const float*)d_in[3];
  const float* bhh0 = (const float*)d_in[4];
  const float* Wih1 = (const float*)d_in[5];
  const float* Whh1 = (const float*)d_in[6];
  const float* bih1 = (const float*)d_in[7];
  const float* bhh1 = (const float*)d_in[8];
  const float* Wfc  = (const float*)d_in[9];
  const float* bfc  = (const float*)d_in[10];
  float* out = (float*)d_out;
  char*  ws  = (char*)d_ws;

  __bf16* xbf  = (__bf16*)(ws + OFF_XBF);
  __bf16* w0x  = (__bf16*)(ws + OFF_W0X);
  __bf16* w0h  = (__bf16*)(ws + OFF_W0H);
  __bf16* w1x  = (__bf16*)(ws + OFF_W1X);
  __bf16* w1h  = (__bf16*)(ws + OFF_W1H);
  float*  b0   = (float*) (ws + OFF_B0);
  float*  b1   = (float*) (ws + OFF_B1);
  __bf16* apub = (__bf16*)(ws + OFF_APUB);
  __bf16* bpub = (__bf16*)(ws + OFF_BPUB);
  unsigned* syncw = (unsigned*)(ws + OFF_SYNC);

  {
    const int n4 = (B_*T_*CIN)/4;
    k_prep_x<<<(n4 + 255)/256, 256, 0, stream>>>(x, xbf);
  }
  {
    const int tot = G4*CIN + 3*G4*H_;
    k_prep_w<<<(tot + 255)/256, 256, 0, stream>>>(Wih0, Whh0, Wih1, Whh1, w0x, w0h, w1x, w1h);
  }
  {
    const int tot = 2*G4 + (int)((2*SZ_PUB)/4) + SYNC_WORDS;
    k_prep_misc<<<(tot + 255)/256, 256, 0, stream>>>(bih0, bhh0, bih1, bhh1, b0, b1,
                                                     (unsigned*)apub, syncw);
  }
  (void)hipFuncSetAttribute((const void*)k_lstm,
                            hipFuncAttributeMaxDynamicSharedMemorySize, DYN_LDS_BYTES);
  k_lstm<<<NWG, 256, DYN_LDS_BYTES, stream>>>(xbf, w0x, w0h, w1x, w1h, b0, b1,
                                              apub, bpub, syncw, Wfc, bfc, out);
}

// Round 7
// 2609.361 us; speedup vs baseline: 1.3840x; 1.3840x over previous
//
#include <hip/hip_runtime.h>
#include <stdint.h>

// ---------------- problem constants ----------------
#define B_   256
#define T_   512
#define CIN  64
#define H_   256
#define G4   1024   // 4*H
#define NC   6

// ---------------- WG geometry ----------------------
#define MB   32               // batch rows per WG
#define NHU  16               // hidden units per WG
#define NBG  (B_/MB)          // 8 batch groups
#define NHG  (H_/NHU)         // 16 hidden groups
#define NWG  (NBG*NHG)        // 128 workgroups

typedef __bf16 bf16x8 __attribute__((ext_vector_type(8)));
typedef __bf16 bf16x4 __attribute__((ext_vector_type(4)));
typedef float  f32x4  __attribute__((ext_vector_type(4)));

// ---------------- workspace layout (bytes) ---------
#define OFF_XBF   ((size_t)0)
#define SZ_XBF    ((size_t)B_*T_*CIN*2)          // 16 MB
#define OFF_W0X   (OFF_XBF + SZ_XBF)
#define SZ_W0X    ((size_t)G4*CIN*2)             // 128 KB
#define OFF_W0H   (OFF_W0X + SZ_W0X)
#define SZ_WH     ((size_t)G4*H_*2)              // 512 KB
#define OFF_W1X   (OFF_W0H + SZ_WH)
#define OFF_W1H   (OFF_W1X + SZ_WH)
#define OFF_B0    (OFF_W1H + SZ_WH)
#define OFF_B1    (OFF_B0 + 4096)
#define OFF_APUB  (OFF_B1 + 4096)
#define SZ_PUB    ((size_t)2*B_*H_*2)            // 256 KB (2 slots)
#define OFF_BPUB  (OFF_APUB + SZ_PUB)
#define OFF_SYNC  (OFF_BPUB + SZ_PUB)
#define SYNC_WORDS 512                           // 8 bg x 64 words (one 64B line used each)

#define DYN_LDS_ELEMS (4096 + 3*16384)           // 53248 bf16
#define DYN_LDS_BYTES (DYN_LDS_ELEMS*2)          // 106496 B

__device__ __forceinline__ f32x4 MFMA(bf16x8 a, bf16x8 b, f32x4 c) {
  return __builtin_amdgcn_mfma_f32_16x16x32_bf16(a, b, c, 0, 0, 0);
}
__device__ __forceinline__ float fsig(float x) { return 1.f/(1.f + __expf(-x)); }
__device__ __forceinline__ float ftanh_(float x) {
  float xx = fminf(fmaxf(x, -15.f), 15.f);
  float t = __expf(2.f*xx);
  return (t-1.f)/(t+1.f);
}

// batched 8x16B coherence-point loads (MALL), no wait inside
__device__ __forceinline__ void load8_c(const __bf16* b, bf16x8 (&r)[8]) {
  const __bf16 *p0=b,      *p1=b+32,  *p2=b+64,  *p3=b+96,
               *p4=b+128,  *p5=b+160, *p6=b+192, *p7=b+224;
  asm volatile(
    "global_load_dwordx4 %0, %8, off sc0 sc1\n\t"
    "global_load_dwordx4 %1, %9, off sc0 sc1\n\t"
    "global_load_dwordx4 %2, %10, off sc0 sc1\n\t"
    "global_load_dwordx4 %3, %11, off sc0 sc1\n\t"
    "global_load_dwordx4 %4, %12, off sc0 sc1\n\t"
    "global_load_dwordx4 %5, %13, off sc0 sc1\n\t"
    "global_load_dwordx4 %6, %14, off sc0 sc1\n\t"
    "global_load_dwordx4 %7, %15, off sc0 sc1"
    : "=&v"(r[0]), "=&v"(r[1]), "=&v"(r[2]), "=&v"(r[3]),
      "=&v"(r[4]), "=&v"(r[5]), "=&v"(r[6]), "=&v"(r[7])
    : "v"(p0), "v"(p1), "v"(p2), "v"(p3), "v"(p4), "v"(p5), "v"(p6), "v"(p7)
    : "memory");
}
__device__ __forceinline__ void waitv0() { asm volatile("s_waitcnt vmcnt(0)" ::: "memory"); }
__device__ __forceinline__ void sbar0()  { __builtin_amdgcn_sched_barrier(0); }

// one-wave, one-line rendezvous poll: 16 stamp words per bg (one 64B line).
// lane i loads word (i&15); detect when all 16 stamps >= tgt. One line
// request per poll round per WG (round-2 rate, no RMW anywhere).
__device__ __forceinline__ void poll16(const unsigned* fb, unsigned tgt) {
  const unsigned* p = fb + (threadIdx.x & 15);
  for (;;) {
    unsigned v;
    asm volatile("global_load_dword %0, %1, off sc0 sc1\n\ts_waitcnt vmcnt(0)"
                 : "=&v"(v) : "v"(p) : "memory");
    if (__ballot(v >= tgt) == ~0ull) return;
    __builtin_amdgcn_s_sleep(1);
  }
}
// per-WG arrival stamp: plain coherent store (no atomic)
__device__ __forceinline__ void store_stamp(unsigned* p, unsigned v) {
  asm volatile("global_store_dword %0, %1, off sc0 sc1" :: "v"(p), "v"(v) : "memory");
}
// write-through 2B store to the coherence point (MALL-allocating: no nt)
__device__ __forceinline__ void store_h16(__bf16* p, float v) {
  __bf16 h = (__bf16)v;
  unsigned u = (unsigned)__builtin_bit_cast(unsigned short, h);
  asm volatile("global_store_short %0, %1, off sc0 sc1" :: "v"(p), "v"(u) : "memory");
}

// ---------------- prep: x -> bf16 ------------------
__global__ void k_prep_x(const float* __restrict__ x, __bf16* __restrict__ xbf) {
  int i = blockIdx.x * blockDim.x + threadIdx.x;
  const int n4 = (B_*T_*CIN)/4;
  if (i >= n4) return;
  float4 v = reinterpret_cast<const float4*>(x)[i];
  bf16x4 o;
  o[0] = (__bf16)v.x; o[1] = (__bf16)v.y; o[2] = (__bf16)v.z; o[3] = (__bf16)v.w;
  reinterpret_cast<bf16x4*>(xbf)[i] = o;
}

// ---------------- prep: weights into MFMA-fragment order ----------------
// target layout per matrix: [hj][ct][ks][sub][col][j]  (j=8 contiguous bf16)
// element = W[g=ct*256+hj*16+col][k=ks*32+sub*8+j]
__global__ void k_prep_w(const float* __restrict__ Wih0, const float* __restrict__ Whh0,
                         const float* __restrict__ Wih1, const float* __restrict__ Whh1,
                         __bf16* __restrict__ w0x, __bf16* __restrict__ w0h,
                         __bf16* __restrict__ w1x, __bf16* __restrict__ w1h) {
  int e = blockIdx.x * blockDim.x + threadIdx.x;
  const int E0 = G4*CIN, E1 = G4*H_;
  const float* W; __bf16* dst; int K; int idx;
  if      (e < E0)        { W = Wih0; dst = w0x; K = CIN; idx = e; }
  else if (e < E0+E1)     { W = Whh0; dst = w0h; K = H_;  idx = e - E0; }
  else if (e < E0+2*E1)   { W = Wih1; dst = w1x; K = H_;  idx = e - E0 - E1; }
  else if (e < E0+3*E1)   { W = Whh1; dst = w1h; K = H_;  idx = e - E0 - 2*E1; }
  else return;
  const int kb = K >> 5;                  // K/32
  int j   = idx & 7;
  int cl  = (idx >> 3) & 15;
  int sb  = (idx >> 7) & 3;
  int ks  = (idx >> 9) % kb;
  int ct  = (idx / (512*kb)) & 3;
  int hj  =  idx / (2048*kb);
  int g  = ct*256 + hj*16 + cl;
  int kk = ks*32 + sb*8 + j;
  dst[idx] = (__bf16)W[(size_t)g*K + kk];
}

// ---------------- prep: biases, zero pub buffers, zero stamps ----------------
__global__ void k_prep_misc(const float* __restrict__ bih0, const float* __restrict__ bhh0,
                            const float* __restrict__ bih1, const float* __restrict__ bhh1,
                            float* __restrict__ bias0, float* __restrict__ bias1,
                            unsigned* __restrict__ zpub, unsigned* __restrict__ syncw) {
  int i = blockIdx.x * blockDim.x + threadIdx.x;
  if (i < G4) bias0[i] = bih0[i] + bhh0[i];
  else if (i < 2*G4) { int j = i - G4; bias1[j] = bih1[j] + bhh1[j]; }
  const int PW = (int)((2*SZ_PUB)/4);
  int zi = i - 2*G4;
  if (zi >= 0 && zi < PW) zpub[zi] = 0u;   // apub+bpub contiguous
  if (i < SYNC_WORDS) syncw[i] = 0u;
}

// ---------------- persistent pipelined LSTM ----------------
// stamp map: bg's line = sync[bg*64 .. bg*64+15]; word hj = "WG (bg,hj) finished iter k" (value k+1)
__global__ void __launch_bounds__(256, 1) k_lstm(
    const __bf16* __restrict__ xbf,
    const __bf16* __restrict__ w0x_g, const __bf16* __restrict__ w0h_g,
    const __bf16* __restrict__ w1x_g, const __bf16* __restrict__ w1h_g,
    const float* __restrict__ bias0, const float* __restrict__ bias1,
    __bf16* __restrict__ apub, __bf16* __restrict__ bpub,
    unsigned* __restrict__ sync,
    const float* __restrict__ Wfc, const float* __restrict__ bfc,
    float* __restrict__ out)
{
  extern __shared__ __bf16 lds[];
  __bf16* l0x = lds;                 // 4096  elems
  __bf16* l0h = lds + 4096;          // 16384
  __bf16* l1x = lds + 20480;         // 16384
  __bf16* l1h = lds + 36864;         // 16384
  __shared__ float s_log[MB][NC];

  const int tid   = threadIdx.x;
  const int bid   = blockIdx.x;
  const int bg    = bid & 7;         // L2-locality heuristic only (correctness-neutral)
  const int hj    = bid >> 3;        // 0..15 hidden group (16 units)
  const int wave  = tid >> 6;
  const int lane  = tid & 63;
  const int layer = wave >> 1;       // waves 0,1 -> layer0 ; waves 2,3 -> layer1
  const int mt    = wave & 1;        // m-tile within the 32-row batch group
  const int col   = lane & 15;       // MFMA A-row / D-col index
  const int sub   = lane >> 4;       // MFMA k-group
  const int brow  = bg*MB + mt*16;

  unsigned* stline = sync + (size_t)bg*64;   // this bg's 16 stamp words (one line)
  unsigned* myst   = stline + hj;

  // stage weights LDS-resident for the whole run
  {
    const uint4* s; uint4* d;
    s = (const uint4*)(w0x_g + (size_t)hj*4096);  d = (uint4*)l0x;
    for (int i = tid; i < 512;  i += 256) d[i] = s[i];
    s = (const uint4*)(w0h_g + (size_t)hj*16384); d = (uint4*)l0h;
    for (int i = tid; i < 2048; i += 256) d[i] = s[i];
    s = (const uint4*)(w1x_g + (size_t)hj*16384); d = (uint4*)l1x;
    for (int i = tid; i < 2048; i += 256) d[i] = s[i];
    s = (const uint4*)(w1h_g + (size_t)hj*16384); d = (uint4*)l1h;
    for (int i = tid; i < 2048; i += 256) d[i] = s[i];
  }
  __syncthreads();

  // per-lane gate biases (unit = hj*16+col), per this wave's layer
  float bs0, bs1, bs2, bs3;
  {
    const float* bp = layer ? bias1 : bias0;
    bs0 = bp[0*256 + hj*16 + col];
    bs1 = bp[1*256 + hj*16 + col];
    bs2 = bp[2*256 + hj*16 + col];
    bs3 = bp[3*256 + hj*16 + col];
  }
  float cst[4] = {0.f, 0.f, 0.f, 0.f};   // c-state for this lane's 4 (row,unit) cells

  for (int k = 0; k <= T_; ++k) {
    const __bf16* a_prev = apub + (size_t)((k+1)&1)*(B_*H_);
    const __bf16* b_prev = bpub + (size_t)((k+1)&1)*(B_*H_);
    __bf16* a_cur = apub + (size_t)(k&1)*(B_*H_);
    __bf16* b_cur = bpub + (size_t)(k&1)*(B_*H_);
    const bool act0 = (layer == 0) && (k < T_);
    const bool act1 = (layer == 1) && (k >= 1);
    f32x4 acc0 = {0,0,0,0}, acc1 = {0,0,0,0}, acc2 = {0,0,0,0}, acc3 = {0,0,0,0};

    // phase A (no dependence on published data): x-input GEMM, K=64
    if (act0) {
      const __bf16* xr = xbf + ((size_t)(brow+col)*T_ + k)*CIN + sub*8;
      const __bf16* wb = l0x + sub*128 + col*8;
#pragma unroll
      for (int ks = 0; ks < 2; ++ks) {
        bf16x8 a = *(const bf16x8*)(xr + ks*32);
        acc0 = MFMA(a, *(const bf16x8*)(wb + ks*512 +    0), acc0);
        acc1 = MFMA(a, *(const bf16x8*)(wb + ks*512 + 1024), acc1);
        acc2 = MFMA(a, *(const bf16x8*)(wb + ks*512 + 2048), acc2);
        acc3 = MFMA(a, *(const bf16x8*)(wb + ks*512 + 3072), acc3);
      }
    }

    // rendezvous: wave 0 polls the bg's 16 stamps (one line request/round),
    // then the block barrier releases everyone. Same DAG as round 2.
    if (k > 0) {
      if (tid < 64) poll16(stline, (unsigned)k);
      __syncthreads();
    }

    // phase B: recurrent GEMMs (operands via coherence-point loads)
    if (act0) {            // gates0 += a_{k-1} @ Whh0^T
      bf16x8 ra[8];
      load8_c(a_prev + (size_t)(brow+col)*H_ + sub*8, ra);
      waitv0(); sbar0();
      const __bf16* wb = l0h + sub*128 + col*8;
#pragma unroll
      for (int ks = 0; ks < 8; ++ks) {
        acc0 = MFMA(ra[ks], *(const bf16x8*)(wb + ks*512 +     0), acc0);
        acc1 = MFMA(ra[ks], *(const bf16x8*)(wb + ks*512 +  4096), acc1);
        acc2 = MFMA(ra[ks], *(const bf16x8*)(wb + ks*512 +  8192), acc2);
        acc3 = MFMA(ra[ks], *(const bf16x8*)(wb + ks*512 + 12288), acc3);
      }
    } else if (act1) {     // gates1 = a_{k-1} @ Wih1^T + b_{k-2} @ Whh1^T
      bf16x8 ra[8], rb[8];
      load8_c(a_prev + (size_t)(brow+col)*H_ + sub*8, ra);
      load8_c(b_prev + (size_t)(brow+col)*H_ + sub*8, rb);
      waitv0(); sbar0();
      const __bf16* w1 = l1x + sub*128 + col*8;
      const __bf16* w2 = l1h + sub*128 + col*8;
#pragma unroll
      for (int ks = 0; ks < 8; ++ks) {
        acc0 = MFMA(ra[ks], *(const bf16x8*)(w1 + ks*512 +     0), acc0);
        acc1 = MFMA(ra[ks], *(const bf16x8*)(w1 + ks*512 +  4096), acc1);
        acc2 = MFMA(ra[ks], *(const bf16x8*)(w1 + ks*512 +  8192), acc2);
        acc3 = MFMA(ra[ks], *(const bf16x8*)(w1 + ks*512 + 12288), acc3);
      }
#pragma unroll
      for (int ks = 0; ks < 8; ++ks) {
        acc0 = MFMA(rb[ks], *(const bf16x8*)(w2 + ks*512 +     0), acc0);
        acc1 = MFMA(rb[ks], *(const bf16x8*)(w2 + ks*512 +  4096), acc1);
        acc2 = MFMA(rb[ks], *(const bf16x8*)(w2 + ks*512 +  8192), acc2);
        acc3 = MFMA(rb[ks], *(const bf16x8*)(w2 + ks*512 + 12288), acc3);
      }
    }

    // elementwise LSTM cell + publish h (write-through bf16, MALL-allocating)
    if (act0 || act1) {
      __bf16* dst  = act0 ? a_cur : b_cur;
      __bf16* drow = dst + (size_t)(brow + sub*4)*H_ + hj*NHU + col;
#pragma unroll
      for (int q = 0; q < 4; ++q) {
        float gi = acc0[q] + bs0;
        float gf = acc1[q] + bs1;
        float gg = acc2[q] + bs2;
        float go = acc3[q] + bs3;
        float si = fsig(gi), sf = fsig(gf), sg = ftanh_(gg), so = fsig(go);
        float c = sf*cst[q] + si*sg;
        cst[q] = c;
        store_h16(drow + (size_t)q*H_, so * ftanh_(c));
      }
    }

    // arrive: drain own stores; barrier = whole WG drained; one stamp store
    waitv0();
    __syncthreads();
    if (tid == 0) store_stamp(myst, (unsigned)(k + 1));
  }

  // ---------------- final FC + softmax (one WG per batch group) ----------------
  if (hj == 0) {
    if (tid < 64) poll16(stline, (unsigned)(T_ + 1));
    __syncthreads();
    // b_{T-1} lives in bpub slot (T_ & 1) == 0
    if (tid < MB*NC) {
      int r = tid / NC, cl = tid % NC;
      const __bf16* hr = bpub + (size_t)(bg*MB + r)*H_;
      const float*  wr = Wfc + (size_t)cl*H_;
      float s = bfc[cl];
      for (int c8 = 0; c8 < 32; ++c8) {
        bf16x8 v;
        const __bf16* p = hr + c8*8;
        asm volatile("global_load_dwordx4 %0, %1, off sc0 sc1\n\ts_waitcnt vmcnt(0)"
                     : "=&v"(v) : "v"(p) : "memory");
#pragma unroll
        for (int j = 0; j < 8; ++j) s = fmaf((float)v[j], wr[c8*8+j], s);
      }
      s_log[r][cl] = s;
    }
    __syncthreads();
    if (tid < MB) {
      float mx = s_log[tid][0];
#pragma unroll
      for (int c2 = 1; c2 < NC; ++c2) mx = fmaxf(mx, s_log[tid][c2]);
      float e[NC]; float se = 0.f;
#pragma unroll
      for (int c2 = 0; c2 < NC; ++c2) { e[c2] = __expf(s_log[tid][c2] - mx); se += e[c2]; }
      float inv = 1.f/se;
#pragma unroll
      for (int c2 = 0; c2 < NC; ++c2) out[(size_t)(bg*MB + tid)*NC + c2] = e[c2]*inv;
    }
  }
}

// ---------------- host launcher ----------------
extern "C" void kernel_launch(void* const* d_in, const int* in_sizes, int n_in,
                              void* d_out, int out_size, void* d_ws, size_t ws_size,
                              hipStream_t stream) {
  const float* x    = (const float*)d_in[0];
  const float* Wih0 = (const float*)d_in[1];
  const float* Whh0 = (const float*)d_in[2];
  const float* bih0 = (const float*)d_in[3];
  const float* bhh0 = (const float*)d_in[4];
  const float* Wih1 = (const float*)d_in[5];
  const float* Whh1 = (const float*)d_in[6];
  const float* bih1 = (const float*)d_in[7];
  const float* bhh1 = (const float*)d_in[8];
  const float* Wfc  = (const float*)d_in[9];
  const float* bfc  = (const float*)d_in[10];
  float* out = (float*)d_out;
  char*  ws  = (char*)d_ws;

  __bf16* xbf  = (__bf16*)(ws + OFF_XBF);
  __bf16* w0x  = (__bf16*)(ws + OFF_W0X);
  __bf16* w0h  = (__bf16*)(ws + OFF_W0H);
  __bf16* w1x  = (__bf16*)(ws + OFF_W1X);
  __bf16* w1h  = (__bf16*)(ws + OFF_W1H);
  float*  b0   = (float*) (ws + OFF_B0);
  float*  b1   = (float*) (ws + OFF_B1);
  __bf16* apub = (__bf16*)(ws + OFF_APUB);
  __bf16* bpub = (__bf16*)(ws + OFF_BPUB);
  unsigned* syncw = (unsigned*)(ws + OFF_SYNC);

  {
    const int n4 = (B_*T_*CIN)/4;
    k_prep_x<<<(n4 + 255)/256, 256, 0, stream>>>(x, xbf);
  }
  {
    const int tot = G4*CIN + 3*G4*H_;
    k_prep_w<<<(tot + 255)/256, 256, 0, stream>>>(Wih0, Whh0, Wih1, Whh1, w0x, w0h, w1x, w1h);
  }
  {
    const int tot = 2*G4 + (int)((2*SZ_PUB)/4);
    k_prep_misc<<<(tot + 255)/256, 256, 0, stream>>>(bih0, bhh0, bih1, bhh1, b0, b1,
                                                     (unsigned*)apub, syncw);
  }
  (void)hipFuncSetAttribute((const void*)k_lstm,
                            hipFuncAttributeMaxDynamicSharedMemorySize, DYN_LDS_BYTES);
  k_lstm<<<NWG, 256, DYN_LDS_BYTES, stream>>>(xbf, w0x, w0h, w1x, w1h, b0, b1,
                                              apub, bpub, syncw, Wfc, bfc, out);
}